// Round 15
// baseline (1302.885 us; speedup 1.0000x reference)
//
#include <hip/hip_runtime.h>
#include <hip/hip_bf16.h>

// ConcatModel (all I/O f32; internal MFMA bf16, f32 accumulate):
// embed-gather(cvt) -> input-proj GEMM (N-major grid; paired-16B fragment xp)
// -> persistent LSTM recurrence (32 grps x 32 rows, 16 wgs/grp, 2 wg/CU;
// FINE-GRAINED per-chunk rendezvous: chunk kt needs only slots {2kt,2kt+1},
// consumption rotated to start at own chunk; agent-scope atomic polls (proven);
// XCD-vote L2 fast path for h) -> feat -> (BN -> GEMM+ReLU) x2 -> BN -> out.

typedef __attribute__((ext_vector_type(8))) short bf16x8;
typedef __attribute__((ext_vector_type(4))) float f32x4;
typedef __attribute__((ext_vector_type(2))) unsigned int u32x2;

#define DEVI __device__ __forceinline__

template<int N> struct IC { static constexpr int v = N; };

template<int AUX> DEVI void async16t(const void* g, void* l) {
  __builtin_amdgcn_global_load_lds((const __attribute__((address_space(1))) void*)g,
                                   (__attribute__((address_space(3))) void*)l,
                                   16, 0, AUX);
}
DEVI void async16(const void* g, void* l) { async16t<0>(g, l); }
DEVI u32x2 load8_pin(const void* addr) {
  u32x2 r;
  asm volatile("global_load_dwordx2 %0, %1, off" : "=v"(r) : "v"(addr) : "memory");
  return r;
}
DEVI void storeh_coh(void* a, unsigned int v) {
  asm volatile("global_store_short %0, %1, off sc0 sc1" ::"v"(a), "v"(v) : "memory");
}
template<int N> DEVI void vmwait_barrier() {
  asm volatile("s_waitcnt vmcnt(%0)" ::"i"(N) : "memory");
  __builtin_amdgcn_s_barrier();
  __builtin_amdgcn_sched_barrier(0);
}
DEVI float rcp_(float x) {
  float r;
  asm("v_rcp_f32 %0, %1" : "=v"(r) : "v"(x));
  return r;
}
DEVI float sigmf_(float x) { return rcp_(1.f + __expf(-x)); }
DEVI float tanhf_(float x) {
  float a = __expf(-2.f * fabsf(x));
  return copysignf((1.f - a) * rcp_(1.f + a), x);
}
DEVI __hip_bfloat16 f2b(float x) { return __float2bfloat16(x); }
DEVI float b2f(__hip_bfloat16 x) { return __bfloat162float(x); }

// ---------------------------------------------------------------------------
__global__ void cvt_f32_bf16(const float* __restrict__ src,
                             __hip_bfloat16* __restrict__ dst, int n4) {
  int i = blockIdx.x * 256 + threadIdx.x;
  int stride = gridDim.x * 256;
  for (; i < n4; i += stride) {
    float4 v = ((const float4*)src)[i];
    union { __hip_bfloat16 h[4]; uint2 u; } o;
    o.h[0] = f2b(v.x); o.h[1] = f2b(v.y); o.h[2] = f2b(v.z); o.h[3] = f2b(v.w);
    ((uint2*)dst)[i] = o.u;
  }
}

// pack W_ih (pad 300->320) + convert W_hh + build biasL, one kernel
__global__ void pack_weights(const float* __restrict__ W_ih,
                             const float* __restrict__ W_hh,
                             const float* __restrict__ b_ih,
                             const float* __restrict__ b_hh,
                             __hip_bfloat16* __restrict__ WihP,
                             __hip_bfloat16* __restrict__ Whhb,
                             float* __restrict__ biasL) {
  int tid = blockIdx.x * 256 + threadIdx.x;
  int stride = gridDim.x * 256;
  for (int i = tid; i < 2048 * 320; i += stride) {
    int r = i / 320, c = i - r * 320;
    WihP[i] = (c < 300) ? f2b(W_ih[r * 300 + c]) : f2b(0.f);
  }
  for (int i = tid; i < 2048 * 512 / 4; i += stride) {
    float4 v = ((const float4*)W_hh)[i];
    union { __hip_bfloat16 h[4]; uint2 u; } o;
    o.h[0] = f2b(v.x); o.h[1] = f2b(v.y); o.h[2] = f2b(v.z); o.h[3] = f2b(v.w);
    ((uint2*)Whhb)[i] = o.u;
  }
  if (tid < 2048) biasL[tid] = b_ih[tid] + b_hh[tid];
}

__global__ void gather_kernel(const int* __restrict__ prem, const int* __restrict__ hyp,
                              const float* __restrict__ embed,
                              __hip_bfloat16* __restrict__ Ain) {
  int row = blockIdx.x * 4 + (threadIdx.x >> 6);
  int lane = threadIdx.x & 63;
  int tt = row >> 9, n = row & 511;
  int tok = (n < 256) ? prem[tt * 256 + n] : hyp[tt * 256 + (n - 256)];
  const float4* e4 = (const float4*)(embed + (size_t)tok * 300);  // 75 x 16B
  uint2* d2 = (uint2*)(Ain + (size_t)row * 320);                  // 80 x 8B
  for (int j = lane; j < 75; j += 64) {
    float4 v = e4[j];
    union { __hip_bfloat16 h[4]; uint2 u; } o;
    o.h[0] = f2b(v.x); o.h[1] = f2b(v.y); o.h[2] = f2b(v.z); o.h[3] = f2b(v.w);
    d2[j] = o.u;
  }
  for (int j = 75 + lane; j < 80; j += 64) d2[j] = make_uint2(0u, 0u);
}

// ---------------------------------------------------------------------------
// Pipelined GEMM, N-MAJOR GRID (m-block = blockIdx.y). EPI=1: f32+bias+relu.
// EPI=2: bf16 fragment layout, paired 16B stores:
// slotP = ((bx*16+by)*4+wid)*8 + i*2 + (j>>1), byte = slotP*1024+lane*16+(j&1)*8.
template<int BM, int EPI>
__global__ __launch_bounds__(256)
void gemm_pipe(const __hip_bfloat16* __restrict__ A,
               const __hip_bfloat16* __restrict__ Bn,
               const float* __restrict__ bias,
               void* __restrict__ Cout, int K, int ldc) {
  constexpr int BK = 64;
  constexpr int ABYT = BM * BK * 2;
  constexpr int BBYT = 128 * BK * 2;
  constexpr int APW = BM / 32;
  constexpr int IFL = APW + 4;
  constexpr int WM = BM / 2, MT = WM / 16;
  __shared__ alignas(16) char smem[2 * ABYT + 2 * BBYT];

  const int tid = threadIdx.x, lane = tid & 63, wid = tid >> 6;
  const int wrow = wid >> 1, wcol = wid & 1;
  const int bx = blockIdx.y, by = blockIdx.x;  // N-major
  const int m0 = bx * BM, n0 = by * 128;
  const int l8 = lane & 7, ld8 = lane >> 3;
  const int swz = (l8 ^ ld8) * 8;

  const __hip_bfloat16* Abase = A + (size_t)m0 * K;
  const __hip_bfloat16* Bbase = Bn + (size_t)n0 * K;

  f32x4 acc[MT][4];
#pragma unroll
  for (int i = 0; i < MT; ++i)
#pragma unroll
    for (int j = 0; j < 4; ++j) acc[i][j] = {0.f, 0.f, 0.f, 0.f};

  auto stage = [&](int buf, int kt) {
    const __hip_bfloat16* as = Abase + kt * BK + swz;
    char* ad = smem + buf * ABYT;
#pragma unroll
    for (int s = 0; s < APW; ++s) {
      int iss = wid * APW + s;
      async16(as + (size_t)(iss * 8 + ld8) * K, ad + iss * 1024);
    }
    const __hip_bfloat16* bs = Bbase + kt * BK + swz;
    char* bd = smem + 2 * ABYT + buf * BBYT;
#pragma unroll
    for (int s = 0; s < 4; ++s) {
      int iss = wid * 4 + s;
      async16(bs + (size_t)(iss * 8 + ld8) * K, bd + iss * 1024);
    }
  };

  const int nk = K / BK;
  stage(0, 0);
  for (int kt = 0; kt < nk; ++kt) {
    if (kt + 1 < nk) {
      stage((kt + 1) & 1, kt + 1);
      vmwait_barrier<IFL>();
    } else {
      vmwait_barrier<0>();
    }
    const __hip_bfloat16* ab = (const __hip_bfloat16*)(smem + (kt & 1) * ABYT);
    const __hip_bfloat16* bb = (const __hip_bfloat16*)(smem + 2 * ABYT + (kt & 1) * BBYT);
#pragma unroll
    for (int kk = 0; kk < BK; kk += 32) {
      bf16x8 af[MT], bf[4];
#pragma unroll
      for (int i = 0; i < MT; ++i) {
        int r = wrow * WM + i * 16 + (lane & 15);
        af[i] = *(const bf16x8*)&ab[r * BK + ((kk + (lane >> 4) * 8) ^ ((r & 7) * 8))];
      }
#pragma unroll
      for (int j = 0; j < 4; ++j) {
        int r = wcol * 64 + j * 16 + (lane & 15);
        bf[j] = *(const bf16x8*)&bb[r * BK + ((kk + (lane >> 4) * 8) ^ ((r & 7) * 8))];
      }
#pragma unroll
      for (int i = 0; i < MT; ++i)
#pragma unroll
        for (int j = 0; j < 4; ++j)
          acc[i][j] = __builtin_amdgcn_mfma_f32_16x16x32_bf16(af[i], bf[j], acc[i][j], 0, 0, 0);
    }
    __builtin_amdgcn_s_barrier();
  }

  if (EPI == 2) {
#pragma unroll
    for (int i = 0; i < MT; ++i)
#pragma unroll
      for (int jp = 0; jp < 2; ++jp) {
        union { __hip_bfloat16 h[8]; uint4 u; } o;
#pragma unroll
        for (int rr = 0; rr < 4; ++rr) {
          o.h[rr] = f2b(acc[i][2 * jp][rr]);
          o.h[4 + rr] = f2b(acc[i][2 * jp + 1][rr]);
        }
        size_t slotP = (((size_t)bx * 16 + by) * 4 + wid) * 8 + i * 2 + jp;
        *(uint4*)((char*)Cout + slotP * 1024 + lane * 16) = o.u;
      }
    return;
  }

  __syncthreads();
  float* Csm = (float*)smem;
#pragma unroll
  for (int i = 0; i < MT; ++i)
#pragma unroll
    for (int j = 0; j < 4; ++j)
#pragma unroll
      for (int rr = 0; rr < 4; ++rr) {
        int row = wrow * WM + i * 16 + (lane >> 4) * 4 + rr;
        int col = wcol * 64 + j * 16 + (lane & 15);
        Csm[row * 128 + (col ^ ((row & 7) << 2))] = acc[i][j][rr];
      }
  __syncthreads();
#pragma unroll
  for (int it = 0; it < BM / 16; ++it) {
    int idx = it * 256 + tid;
    int row = idx >> 4;
    int cb = (idx & 15) * 8;
    int sw = (row & 7) << 2;
    float4 v0 = *(const float4*)&Csm[row * 128 + (cb ^ sw)];
    float4 v1 = *(const float4*)&Csm[row * 128 + ((cb + 4) ^ sw)];
    float4 b0 = *(const float4*)&bias[n0 + cb];
    float4 b1 = *(const float4*)&bias[n0 + cb + 4];
    v0.x = fmaxf(v0.x + b0.x, 0.f); v0.y = fmaxf(v0.y + b0.y, 0.f);
    v0.z = fmaxf(v0.z + b0.z, 0.f); v0.w = fmaxf(v0.w + b0.w, 0.f);
    v1.x = fmaxf(v1.x + b1.x, 0.f); v1.y = fmaxf(v1.y + b1.y, 0.f);
    v1.z = fmaxf(v1.z + b1.z, 0.f); v1.w = fmaxf(v1.w + b1.w, 0.f);
    size_t base = (size_t)(m0 + row) * ldc + n0 + cb;
    *(float4*)&((float*)Cout)[base] = v0;
    *(float4*)&((float*)Cout)[base + 4] = v1;
  }
}

// ---------------------------------------------------------------------------
// Persistent recurrence: 512 wgs (2/CU). wg = (gi 0..31 = 32 batch rows,
// jt 0..15 = 32 h-cols). Fine-grained rendezvous: A-chunk kt depends only on
// slots {2kt, 2kt+1}; chunks consumed starting at own chunk (jt>>1), polled
// just-in-time 3 deep. Agent-scope atomic polls (PROVEN — sc0 spin hangs).
// LDS: [0,32K) A chunks (8x4KB, physical index); [32K,48K) gsm; flag @48K.
__global__ __launch_bounds__(256, 2)
void lstm_persist(const __hip_bfloat16* __restrict__ xp,
                  const __hip_bfloat16* __restrict__ Whh,
                  const float* __restrict__ biasL,
                  __hip_bfloat16* __restrict__ hA,
                  __hip_bfloat16* __restrict__ hB,
                  int* __restrict__ ctr) {
  extern __shared__ char smem[];
  const int tid = threadIdx.x, lane = tid & 63, wid = tid >> 6;
  const int bid = blockIdx.x;
  const int gi = (bid & 7) | ((bid >> 7) << 3);  // 16 jt-wgs share gi
  const int jt = (bid >> 3) & 15;
  const int gl = (gi < 16) ? gi : gi - 16;
  const int m0 = (gi < 16) ? gi * 32 : 512 + gl * 32;
  const int l8 = lane & 7, ld8 = lane >> 3;
  const int swz = (l8 ^ ld8) * 8;

  // ---- one-time: W slice (4 gates x 32 rows x 512 K) -> w[2][16] per wave ----
  bf16x8 w[2][16];
#pragma unroll
  for (int kt = 0; kt < 8; ++kt) {
#pragma unroll
    for (int s = 0; s < 4; ++s) {
      int lr32 = s * 8 + ld8;
      int Wrow = wid * 512 + jt * 32 + lr32;
      async16(Whh + (size_t)Wrow * 512 + kt * 64 + swz,
              smem + wid * 4096 + s * 1024);
    }
    asm volatile("s_waitcnt vmcnt(0)" ::: "memory");
    __builtin_amdgcn_s_barrier();
    __builtin_amdgcn_sched_barrier(0);
    {
      const __hip_bfloat16* wb = (const __hip_bfloat16*)(smem + wid * 4096);
#pragma unroll
      for (int j = 0; j < 2; ++j) {
        int r = j * 16 + (lane & 15);
#pragma unroll
        for (int kkh = 0; kkh < 2; ++kkh)
          w[j][kt * 2 + kkh] =
              *(const bf16x8*)&wb[r * 64 + ((kkh * 32 + (lane >> 4) * 8) ^ ((r & 7) * 8))];
      }
    }
    __syncthreads();
  }

  // ---- one-time: XCD co-location vote (guarded fast path) ----
  int* flag = (int*)(smem + 49152);
  if (tid == 0) {
    int xcd = (int)(__builtin_amdgcn_s_getreg((31 << 11) | 20) & 15);  // HW_REG_XCC_ID
    int o1 = atomicOr(&ctr[512 + gi], 1 << xcd);
    int o2 = atomicOr(&ctr[561], 1 << xcd);
    asm volatile("" ::"v"(o1), "v"(o2));
    atomicAdd(&ctr[560], 1);
    while (__hip_atomic_load(&ctr[560], __ATOMIC_RELAXED, __HIP_MEMORY_SCOPE_AGENT) < 512)
      __builtin_amdgcn_s_sleep(2);
    int gm = __hip_atomic_load(&ctr[512 + gi], __ATOMIC_RELAXED, __HIP_MEMORY_SCOPE_AGENT);
    int am = __hip_atomic_load(&ctr[561], __ATOMIC_RELAXED, __HIP_MEMORY_SCOPE_AGENT);
    *flag = (__popc((unsigned)gm) == 1 && __popc((unsigned)am) == 8) ? 1 : 0;
  }
  __syncthreads();
  const bool fastpath = (*flag != 0);
  __syncthreads();

  // ownership / fragment constants
  const int rq = tid >> 5;        // row-quad 0..7
  const int col = tid & 31;       // h-col within jt slice
  const int i_x = (gl & 1) * 2 + (rq >> 2);
  const int wid_x = ((gl & 3) >> 1) * 2 + ((jt & 3) >> 1);
  const int j_x = (jt & 1) * 2 + (col >> 4);
  const int lane_x = ((rq & 3) << 4) | (col & 15);
  const int ktbase = jt >> 1;     // own chunk first; K-sum commutative

  float bias_[4];
#pragma unroll
  for (int g = 0; g < 4; ++g) bias_[g] = biasL[g * 512 + jt * 32 + col];

  float c_[4];
#pragma unroll
  for (int e = 0; e < 4; ++e) c_[e] = 0.f;

  auto run = [&](auto FC) {
    constexpr bool FAST = decltype(FC)::v;
    constexpr int AUX = FAST ? 1 : 17;
    for (int t = 0; t < 64; ++t) {
      const __hip_bfloat16* hin = (t & 1) ? hB : hA;
      __hip_bfloat16* hout = (t & 1) ? hA : hB;

      // xp fragment loads FIRST (h-independent)
      const int TT = (gi < 16) ? t : 63 - t;
      const int bx = TT * 4 + (gl >> 2);
      u32x2 xg[4];
#pragma unroll
      for (int g = 0; g < 4; ++g) {
        int by = g * 4 + (jt >> 2);
        size_t slotP = (((size_t)bx * 16 + by) * 4 + wid_x) * 8 + i_x * 2 + (j_x >> 1);
        xg[g] = load8_pin((const char*)xp + slotP * 1024 + lane_x * 16 + (j_x & 1) * 8);
      }
      __builtin_amdgcn_sched_barrier(0);

      // per-chunk poll: chunk ck needs slots {2ck, 2ck+1} >= t (agent-scope)
      auto pollchunk = [&](int ck) {
        if (t > 0) {
          if (wid == 0) {
            bool ok;
            do {
              int v = (lane < 2)
                          ? __hip_atomic_load(&ctr[gi * 16 + 2 * ck + lane],
                                              __ATOMIC_RELAXED, __HIP_MEMORY_SCOPE_AGENT)
                          : t;
              ok = __all(v >= t);
              if (!ok) __builtin_amdgcn_s_sleep(1);
            } while (!ok);
          }
          __syncthreads();
        }
      };
      auto issueA = [&](int ck) {  // 1 issue/thread into physical buffer ck
        async16t<AUX>(hin + (size_t)(m0 + wid * 8 + ld8) * 512 + ck * 64 + swz,
                      smem + ck * 4096 + wid * 1024);
      };

      // prologue: first 3 chunks (own chunk first -> near-zero wait)
#pragma unroll
      for (int k = 0; k < 3; ++k) {
        int ck = (ktbase + k) & 7;
        pollchunk(ck);
        issueA(ck);
      }
      __builtin_amdgcn_sched_barrier(0);

      f32x4 acc[2][2];
#pragma unroll
      for (int i = 0; i < 2; ++i)
#pragma unroll
        for (int j = 0; j < 2; ++j) acc[i][j] = {0.f, 0.f, 0.f, 0.f};

      auto do_kt = [&](int ck) {
        const __hip_bfloat16* ab = (const __hip_bfloat16*)(smem + ck * 4096);
#pragma unroll
        for (int kk = 0; kk < 64; kk += 32) {
          bf16x8 af[2];
#pragma unroll
          for (int i = 0; i < 2; ++i) {
            int r = i * 16 + (lane & 15);
            af[i] = *(const bf16x8*)&ab[r * 64 + ((kk + (lane >> 4) * 8) ^ ((r & 7) * 8))];
          }
#pragma unroll
          for (int i = 0; i < 2; ++i)
#pragma unroll
            for (int j = 0; j < 2; ++j)
              acc[i][j] = __builtin_amdgcn_mfma_f32_16x16x32_bf16(
                  af[i], w[j][ck * 2 + kk / 32], acc[i][j], 0, 0, 0);
        }
      };
      // issue order: [xp x4][c0..c2][c3..c7 in-loop] -> WT = {3,3,3,3,3,2,1,0}
      auto step_k = [&](auto K) {
        constexpr int KK = decltype(K)::v;
        constexpr int WT[8] = {3, 3, 3, 3, 3, 2, 1, 0};
        if constexpr (KK < 5) {
          int cknext = (ktbase + KK + 3) & 7;
          pollchunk(cknext);
          issueA(cknext);
        }
        vmwait_barrier<WT[KK]>();
        do_kt((ktbase + KK) & 7);
      };
      step_k(IC<0>{}); step_k(IC<1>{}); step_k(IC<2>{}); step_k(IC<3>{});
      step_k(IC<4>{}); step_k(IC<5>{}); step_k(IC<6>{}); step_k(IC<7>{});

      // gate exchange: 16 planes x 1KB, b128 both sides (conflict-free)
      float* gsm = (float*)(smem + 32768);
      __syncthreads();
#pragma unroll
      for (int i = 0; i < 2; ++i)
#pragma unroll
        for (int j = 0; j < 2; ++j)
          *(f32x4*)(gsm + (wid * 4 + i * 2 + j) * 256 + lane * 4) = acc[i][j];
      __syncthreads();
      f32x4 gq[4];
      {
        const int iq = rq >> 2, jq = col >> 4;
        const int lprime = ((rq & 3) << 4) | (col & 15);
#pragma unroll
        for (int g = 0; g < 4; ++g)
          gq[g] = *(const f32x4*)(gsm + (g * 4 + iq * 2 + jq) * 256 + lprime * 4);
      }

      union { u32x2 v; __hip_bfloat16 h[4]; } X[4];
#pragma unroll
      for (int g = 0; g < 4; ++g) X[g].v = xg[g];
      __hip_bfloat16* hbase = hout + (size_t)(m0 + rq * 4) * 512 + jt * 32 + col;
#pragma unroll
      for (int rr = 0; rr < 4; ++rr) {
        float gi_ = gq[0][rr] + b2f(X[0].h[rr]) + bias_[0];
        float gf = gq[1][rr] + b2f(X[1].h[rr]) + bias_[1];
        float gg = gq[2][rr] + b2f(X[2].h[rr]) + bias_[2];
        float go = gq[3][rr] + b2f(X[3].h[rr]) + bias_[3];
        float cn = sigmf_(gf) * c_[rr] + sigmf_(gi_) * tanhf_(gg);
        float hn = sigmf_(go) * tanhf_(cn);
        c_[rr] = cn;
        union { __hip_bfloat16 b; unsigned short u; } hb;
        hb.b = f2b(hn);
        if constexpr (FAST) {
          hbase[rr * 512] = hb.b;  // plain store -> local L2 (same-XCD coherent)
        } else {
          storeh_coh(hbase + rr * 512, (unsigned int)hb.u);
        }
      }
      asm volatile("s_waitcnt vmcnt(0)" ::: "memory");  // h stores acked
      __syncthreads();                                   // whole wg's stores acked
      if (tid == 0)
        __hip_atomic_store(&ctr[gi * 16 + jt], t + 1, __ATOMIC_RELAXED,
                           __HIP_MEMORY_SCOPE_AGENT);
    }
  };
  if (fastpath) run(IC<1>{});
  else          run(IC<0>{});
}

// ---------------------------------------------------------------------------
__global__ void feat_kernel(const __hip_bfloat16* __restrict__ hA, float* __restrict__ feat) {
  int b = blockIdx.x;
  for (int c = threadIdx.x; c < 2048; c += 256) {
    int sec = c >> 9, j = c & 511;
    int row = (sec == 0) ? b : (sec == 1) ? 512 + b : (sec == 2) ? 256 + b : 768 + b;
    feat[b * 2048 + c] = b2f(hA[(size_t)row * 512 + j]);
  }
}

__global__ void bn_stats(const float* __restrict__ x, const float* __restrict__ g,
                         const float* __restrict__ b,
                         float* __restrict__ sc, float* __restrict__ sh) {
  int c = blockIdx.x * 256 + threadIdx.x;
  float s = 0.f, s2 = 0.f;
  for (int r = 0; r < 256; ++r) {
    float v = x[r * 2048 + c];
    s += v;
    s2 += v * v;
  }
  float mu = s * (1.f / 256.f);
  float var = s2 * (1.f / 256.f) - mu * mu;
  float rs = rsqrtf(var + 1e-5f);
  float scale = g[c] * rs;
  sc[c] = scale;
  sh[c] = b[c] - mu * scale;
}

__global__ void bn_apply(const float* __restrict__ x, const float* __restrict__ sc,
                         const float* __restrict__ sh, __hip_bfloat16* __restrict__ xn) {
  int i = blockIdx.x * 256 + threadIdx.x;
  int c = i & 2047;
  xn[i] = f2b(x[i] * sc[c] + sh[c]);
}

__global__ void final_kernel(const float* __restrict__ x2, const float* __restrict__ sc,
                             const float* __restrict__ sh, const float* __restrict__ Wo,
                             const float* __restrict__ bo, float* __restrict__ out) {
  __shared__ float red[3][256];
  int b = blockIdx.x, tid = threadIdx.x;
  float a0 = 0.f, a1 = 0.f, a2 = 0.f;
  for (int c = tid; c < 2048; c += 256) {
    float v = x2[b * 2048 + c] * sc[c] + sh[c];
    a0 += v * Wo[c];
    a1 += v * Wo[2048 + c];
    a2 += v * Wo[4096 + c];
  }
  red[0][tid] = a0; red[1][tid] = a1; red[2][tid] = a2;
  __syncthreads();
  for (int s = 128; s > 0; s >>= 1) {
    if (tid < s) {
      red[0][tid] += red[0][tid + s];
      red[1][tid] += red[1][tid + s];
      red[2][tid] += red[2][tid + s];
    }
    __syncthreads();
  }
  if (tid < 3) out[b * 3 + tid] = red[tid][0] + bo[tid];
}

// ---------------------------------------------------------------------------
extern "C" void kernel_launch(void* const* d_in, const int* in_sizes, int n_in,
                              void* d_out, int out_size, void* d_ws, size_t ws_size,
                              hipStream_t stream) {
  (void)in_sizes; (void)n_in; (void)out_size; (void)ws_size;
  const int* prem = (const int*)d_in[0];
  const int* hyp = (const int*)d_in[1];
  const float* embed = (const float*)d_in[2];
  const float* W_ih = (const float*)d_in[3];
  const float* W_hh = (const float*)d_in[4];
  const float* b_ih = (const float*)d_in[5];
  const float* b_hh = (const float*)d_in[6];
  const float* bn0g = (const float*)d_in[7];
  const float* bn0b = (const float*)d_in[8];
  const float* W0 = (const float*)d_in[9];
  const float* b0 = (const float*)d_in[10];
  const float* bn1g = (const float*)d_in[11];
  const float* bn1b = (const float*)d_in[12];
  const float* W1 = (const float*)d_in[13];
  const float* b1 = (const float*)d_in[14];
  const float* bnog = (const float*)d_in[15];
  const float* bnob = (const float*)d_in[16];
  const float* Wo = (const float*)d_in[17];
  const float* bo = (const float*)d_in[18];
  float* out = (float*)d_out;

  char* w = (char*)d_ws;
  size_t off = 0;
  auto alloc = [&](size_t bytes) {
    void* p = w + off;
    off += (bytes + 255) & ~(size_t)255;
    return p;
  };
  __hip_bfloat16* WihP = (__hip_bfloat16*)alloc((size_t)2048 * 320 * 2);
  __hip_bfloat16* Whhb = (__hip_bfloat16*)alloc((size_t)2048 * 512 * 2);
  __hip_bfloat16* W0b = (__hip_bfloat16*)alloc((size_t)2048 * 2048 * 2);
  __hip_bfloat16* W1b = (__hip_bfloat16*)alloc((size_t)2048 * 2048 * 2);
  float* biasL = (float*)alloc(2048 * 4);
  int* ctr = (int*)alloc(1024 * 4);
  __hip_bfloat16* xp = (__hip_bfloat16*)alloc((size_t)32768 * 2048 * 2);  // 128 MiB, fragment layout
  size_t ain_off = off;
  __hip_bfloat16* Ain = (__hip_bfloat16*)alloc((size_t)32768 * 320 * 2);  // 20 MiB
  size_t end_off = off;
  off = ain_off;  // post-GEMM block aliases Ain (dead after xproj)
  __hip_bfloat16* hA = (__hip_bfloat16*)alloc((size_t)1024 * 512 * 2);
  __hip_bfloat16* hB = (__hip_bfloat16*)alloc((size_t)1024 * 512 * 2);
  float* feat = (float*)alloc((size_t)256 * 2048 * 4);
  __hip_bfloat16* xn = (__hip_bfloat16*)alloc((size_t)256 * 2048 * 2);
  float* x1 = (float*)alloc((size_t)256 * 2048 * 4);
  float* x2 = (float*)alloc((size_t)256 * 2048 * 4);
  float* sc0 = (float*)alloc(2048 * 4);
  float* sh0 = (float*)alloc(2048 * 4);
  float* sc1 = (float*)alloc(2048 * 4);
  float* sh1 = (float*)alloc(2048 * 4);
  float* sc2 = (float*)alloc(2048 * 4);
  float* sh2 = (float*)alloc(2048 * 4);
  (void)end_off;

  (void)hipMemsetAsync(ctr, 0, 1024 * 4, stream);  // fresh barrier/vote state EVERY launch
  pack_weights<<<512, 256, 0, stream>>>(W_ih, W_hh, b_ih, b_hh, WihP, Whhb, biasL);
  cvt_f32_bf16<<<2048, 256, 0, stream>>>(W0, W0b, 2048 * 2048 / 4);
  cvt_f32_bf16<<<2048, 256, 0, stream>>>(W1, W1b, 2048 * 2048 / 4);
  gather_kernel<<<8192, 256, 0, stream>>>(prem, hyp, embed, Ain);
  // x_proj (N-major grid; paired-16B fragment layout): M=32768, N=2048, K=320
  gemm_pipe<128, 2><<<dim3(16, 256), 256, 0, stream>>>(Ain, WihP, biasL, xp, 320, 2048);
  (void)hipMemsetAsync(hA, 0, (size_t)1024 * 512 * 2, stream);  // h0 = 0 (aliases Ain)
  // persistent recurrence: 512 wgs, 48.2KB dyn LDS, 2 wg/CU
  (void)hipFuncSetAttribute(reinterpret_cast<const void*>(lstm_persist),
                            hipFuncAttributeMaxDynamicSharedMemorySize, 65536);
  lstm_persist<<<512, 256, 49408, stream>>>(xp, Whhb, biasL, hA, hB, ctr);
  feat_kernel<<<256, 256, 0, stream>>>(hA, feat);  // t=63 wrote hA
  bn_stats<<<8, 256, 0, stream>>>(feat, bn0g, bn0b, sc0, sh0);
  bn_apply<<<2048, 256, 0, stream>>>(feat, sc0, sh0, xn);
  gemm_pipe<64, 1><<<dim3(16, 4), 256, 0, stream>>>(xn, W0b, b0, x1, 2048, 2048);
  bn_stats<<<8, 256, 0, stream>>>(x1, bn1g, bn1b, sc1, sh1);
  bn_apply<<<2048, 256, 0, stream>>>(x1, sc1, sh1, xn);
  gemm_pipe<64, 1><<<dim3(16, 4), 256, 0, stream>>>(xn, W1b, b1, x2, 2048, 2048);
  bn_stats<<<8, 256, 0, stream>>>(x2, bnog, bnob, sc2, sh2);
  final_kernel<<<256, 256, 0, stream>>>(x2, sc2, sh2, Wo, bo, out);
}

// Round 16
// 442.746 us; speedup vs baseline: 2.9427x; 2.9427x over previous
//
#include <hip/hip_runtime.h>
#include <hip/hip_bf16.h>

// ConcatModel (all I/O f32; internal MFMA bf16, f32 accumulate):
// embed-gather(cvt) -> input-proj GEMM (N-major grid for A-reuse; paired-16B
// fragment-layout xp) -> persistent LSTM recurrence (32 grps x 32 rows,
// 16 wgs/grp, 2 wg/CU; SINGLE batched agent-scope slot rendezvous per step
// (per-chunk polling in R15 caused 2.26GB of uncached poll traffic — never
// fine-grain agent-scope spins), XCD-vote L2 fast path for h exchange;
// W_hh in regs, c in regs, rcp activations) -> feat -> (BN -> GEMM+ReLU) x2
// -> BN -> tiny output GEMM.

typedef __attribute__((ext_vector_type(8))) short bf16x8;
typedef __attribute__((ext_vector_type(4))) float f32x4;
typedef __attribute__((ext_vector_type(2))) unsigned int u32x2;

#define DEVI __device__ __forceinline__

template<int N> struct IC { static constexpr int v = N; };

template<int AUX> DEVI void async16t(const void* g, void* l) {
  __builtin_amdgcn_global_load_lds((const __attribute__((address_space(1))) void*)g,
                                   (__attribute__((address_space(3))) void*)l,
                                   16, 0, AUX);
}
DEVI void async16(const void* g, void* l) { async16t<0>(g, l); }
DEVI u32x2 load8_pin(const void* addr) {
  u32x2 r;
  asm volatile("global_load_dwordx2 %0, %1, off" : "=v"(r) : "v"(addr) : "memory");
  return r;
}
DEVI void storeh_coh(void* a, unsigned int v) {
  asm volatile("global_store_short %0, %1, off sc0 sc1" ::"v"(a), "v"(v) : "memory");
}
template<int N> DEVI void vmwait_barrier() {
  asm volatile("s_waitcnt vmcnt(%0)" ::"i"(N) : "memory");
  __builtin_amdgcn_s_barrier();
  __builtin_amdgcn_sched_barrier(0);
}
DEVI float rcp_(float x) {
  float r;
  asm("v_rcp_f32 %0, %1" : "=v"(r) : "v"(x));
  return r;
}
DEVI float sigmf_(float x) { return rcp_(1.f + __expf(-x)); }
DEVI float tanhf_(float x) {
  float a = __expf(-2.f * fabsf(x));
  return copysignf((1.f - a) * rcp_(1.f + a), x);
}
DEVI __hip_bfloat16 f2b(float x) { return __float2bfloat16(x); }
DEVI float b2f(__hip_bfloat16 x) { return __bfloat162float(x); }

// ---------------------------------------------------------------------------
__global__ void cvt_f32_bf16(const float* __restrict__ src,
                             __hip_bfloat16* __restrict__ dst, int n4) {
  int i = blockIdx.x * 256 + threadIdx.x;
  int stride = gridDim.x * 256;
  for (; i < n4; i += stride) {
    float4 v = ((const float4*)src)[i];
    union { __hip_bfloat16 h[4]; uint2 u; } o;
    o.h[0] = f2b(v.x); o.h[1] = f2b(v.y); o.h[2] = f2b(v.z); o.h[3] = f2b(v.w);
    ((uint2*)dst)[i] = o.u;
  }
}

// pack W_ih (pad 300->320) + convert W_hh + build biasL, one kernel
__global__ void pack_weights(const float* __restrict__ W_ih,
                             const float* __restrict__ W_hh,
                             const float* __restrict__ b_ih,
                             const float* __restrict__ b_hh,
                             __hip_bfloat16* __restrict__ WihP,
                             __hip_bfloat16* __restrict__ Whhb,
                             float* __restrict__ biasL) {
  int tid = blockIdx.x * 256 + threadIdx.x;
  int stride = gridDim.x * 256;
  for (int i = tid; i < 2048 * 320; i += stride) {
    int r = i / 320, c = i - r * 320;
    WihP[i] = (c < 300) ? f2b(W_ih[r * 300 + c]) : f2b(0.f);
  }
  for (int i = tid; i < 2048 * 512 / 4; i += stride) {
    float4 v = ((const float4*)W_hh)[i];
    union { __hip_bfloat16 h[4]; uint2 u; } o;
    o.h[0] = f2b(v.x); o.h[1] = f2b(v.y); o.h[2] = f2b(v.z); o.h[3] = f2b(v.w);
    ((uint2*)Whhb)[i] = o.u;
  }
  if (tid < 2048) biasL[tid] = b_ih[tid] + b_hh[tid];
}

__global__ void gather_kernel(const int* __restrict__ prem, const int* __restrict__ hyp,
                              const float* __restrict__ embed,
                              __hip_bfloat16* __restrict__ Ain) {
  int row = blockIdx.x * 4 + (threadIdx.x >> 6);
  int lane = threadIdx.x & 63;
  int tt = row >> 9, n = row & 511;
  int tok = (n < 256) ? prem[tt * 256 + n] : hyp[tt * 256 + (n - 256)];
  const float4* e4 = (const float4*)(embed + (size_t)tok * 300);  // 75 x 16B
  uint2* d2 = (uint2*)(Ain + (size_t)row * 320);                  // 80 x 8B
  for (int j = lane; j < 75; j += 64) {
    float4 v = e4[j];
    union { __hip_bfloat16 h[4]; uint2 u; } o;
    o.h[0] = f2b(v.x); o.h[1] = f2b(v.y); o.h[2] = f2b(v.z); o.h[3] = f2b(v.w);
    d2[j] = o.u;
  }
  for (int j = 75 + lane; j < 80; j += 64) d2[j] = make_uint2(0u, 0u);
}

// ---------------------------------------------------------------------------
// Pipelined GEMM, N-MAJOR GRID: m-block = blockIdx.y, n-block = blockIdx.x,
// so consecutive wgs share one A-tile (L2-hit; A read ~once from HBM).
// EPI=1: f32+bias+relu. EPI=2: bf16 fragment layout, paired 16B stores:
// slotP = ((bx*16+by)*4+wid)*8 + i*2 + (j>>1), byte = slotP*1024+lane*16+(j&1)*8
// with bx = m-block, by = n-block.
template<int BM, int EPI>
__global__ __launch_bounds__(256)
void gemm_pipe(const __hip_bfloat16* __restrict__ A,
               const __hip_bfloat16* __restrict__ Bn,
               const float* __restrict__ bias,
               void* __restrict__ Cout, int K, int ldc) {
  constexpr int BK = 64;
  constexpr int ABYT = BM * BK * 2;
  constexpr int BBYT = 128 * BK * 2;
  constexpr int APW = BM / 32;
  constexpr int IFL = APW + 4;
  constexpr int WM = BM / 2, MT = WM / 16;
  __shared__ alignas(16) char smem[2 * ABYT + 2 * BBYT];

  const int tid = threadIdx.x, lane = tid & 63, wid = tid >> 6;
  const int wrow = wid >> 1, wcol = wid & 1;
  const int bx = blockIdx.y, by = blockIdx.x;  // N-major
  const int m0 = bx * BM, n0 = by * 128;
  const int l8 = lane & 7, ld8 = lane >> 3;
  const int swz = (l8 ^ ld8) * 8;

  const __hip_bfloat16* Abase = A + (size_t)m0 * K;
  const __hip_bfloat16* Bbase = Bn + (size_t)n0 * K;

  f32x4 acc[MT][4];
#pragma unroll
  for (int i = 0; i < MT; ++i)
#pragma unroll
    for (int j = 0; j < 4; ++j) acc[i][j] = {0.f, 0.f, 0.f, 0.f};

  auto stage = [&](int buf, int kt) {
    const __hip_bfloat16* as = Abase + kt * BK + swz;
    char* ad = smem + buf * ABYT;
#pragma unroll
    for (int s = 0; s < APW; ++s) {
      int iss = wid * APW + s;
      async16(as + (size_t)(iss * 8 + ld8) * K, ad + iss * 1024);
    }
    const __hip_bfloat16* bs = Bbase + kt * BK + swz;
    char* bd = smem + 2 * ABYT + buf * BBYT;
#pragma unroll
    for (int s = 0; s < 4; ++s) {
      int iss = wid * 4 + s;
      async16(bs + (size_t)(iss * 8 + ld8) * K, bd + iss * 1024);
    }
  };

  const int nk = K / BK;
  stage(0, 0);
  for (int kt = 0; kt < nk; ++kt) {
    if (kt + 1 < nk) {
      stage((kt + 1) & 1, kt + 1);
      vmwait_barrier<IFL>();
    } else {
      vmwait_barrier<0>();
    }
    const __hip_bfloat16* ab = (const __hip_bfloat16*)(smem + (kt & 1) * ABYT);
    const __hip_bfloat16* bb = (const __hip_bfloat16*)(smem + 2 * ABYT + (kt & 1) * BBYT);
#pragma unroll
    for (int kk = 0; kk < BK; kk += 32) {
      bf16x8 af[MT], bf[4];
#pragma unroll
      for (int i = 0; i < MT; ++i) {
        int r = wrow * WM + i * 16 + (lane & 15);
        af[i] = *(const bf16x8*)&ab[r * BK + ((kk + (lane >> 4) * 8) ^ ((r & 7) * 8))];
      }
#pragma unroll
      for (int j = 0; j < 4; ++j) {
        int r = wcol * 64 + j * 16 + (lane & 15);
        bf[j] = *(const bf16x8*)&bb[r * BK + ((kk + (lane >> 4) * 8) ^ ((r & 7) * 8))];
      }
#pragma unroll
      for (int i = 0; i < MT; ++i)
#pragma unroll
        for (int j = 0; j < 4; ++j)
          acc[i][j] = __builtin_amdgcn_mfma_f32_16x16x32_bf16(af[i], bf[j], acc[i][j], 0, 0, 0);
    }
    __builtin_amdgcn_s_barrier();
  }

  if (EPI == 2) {
#pragma unroll
    for (int i = 0; i < MT; ++i)
#pragma unroll
      for (int jp = 0; jp < 2; ++jp) {
        union { __hip_bfloat16 h[8]; uint4 u; } o;
#pragma unroll
        for (int rr = 0; rr < 4; ++rr) {
          o.h[rr] = f2b(acc[i][2 * jp][rr]);
          o.h[4 + rr] = f2b(acc[i][2 * jp + 1][rr]);
        }
        size_t slotP = (((size_t)bx * 16 + by) * 4 + wid) * 8 + i * 2 + jp;
        *(uint4*)((char*)Cout + slotP * 1024 + lane * 16) = o.u;
      }
    return;
  }

  __syncthreads();
  float* Csm = (float*)smem;
#pragma unroll
  for (int i = 0; i < MT; ++i)
#pragma unroll
    for (int j = 0; j < 4; ++j)
#pragma unroll
      for (int rr = 0; rr < 4; ++rr) {
        int row = wrow * WM + i * 16 + (lane >> 4) * 4 + rr;
        int col = wcol * 64 + j * 16 + (lane & 15);
        Csm[row * 128 + (col ^ ((row & 7) << 2))] = acc[i][j][rr];
      }
  __syncthreads();
#pragma unroll
  for (int it = 0; it < BM / 16; ++it) {
    int idx = it * 256 + tid;
    int row = idx >> 4;
    int cb = (idx & 15) * 8;
    int sw = (row & 7) << 2;
    float4 v0 = *(const float4*)&Csm[row * 128 + (cb ^ sw)];
    float4 v1 = *(const float4*)&Csm[row * 128 + ((cb + 4) ^ sw)];
    float4 b0 = *(const float4*)&bias[n0 + cb];
    float4 b1 = *(const float4*)&bias[n0 + cb + 4];
    v0.x = fmaxf(v0.x + b0.x, 0.f); v0.y = fmaxf(v0.y + b0.y, 0.f);
    v0.z = fmaxf(v0.z + b0.z, 0.f); v0.w = fmaxf(v0.w + b0.w, 0.f);
    v1.x = fmaxf(v1.x + b1.x, 0.f); v1.y = fmaxf(v1.y + b1.y, 0.f);
    v1.z = fmaxf(v1.z + b1.z, 0.f); v1.w = fmaxf(v1.w + b1.w, 0.f);
    size_t base = (size_t)(m0 + row) * ldc + n0 + cb;
    *(float4*)&((float*)Cout)[base] = v0;
    *(float4*)&((float*)Cout)[base + 4] = v1;
  }
}

// ---------------------------------------------------------------------------
// Persistent recurrence: 512 wgs (2/CU). wg = (gi 0..31 = 32 batch rows,
// jt 0..15 = 32 h-cols). FAST path (same-XCD vote): plain h stores + aux=1
// loads through local L2; rendezvous ALWAYS one batched agent-scope poll.
// LDS: [0,32K) full A tile (8x4KB); [32K,48K) gsm 16 planes; flag @48K.
__global__ __launch_bounds__(256, 2)
void lstm_persist(const __hip_bfloat16* __restrict__ xp,
                  const __hip_bfloat16* __restrict__ Whh,
                  const float* __restrict__ biasL,
                  __hip_bfloat16* __restrict__ hA,
                  __hip_bfloat16* __restrict__ hB,
                  int* __restrict__ ctr) {
  extern __shared__ char smem[];
  const int tid = threadIdx.x, lane = tid & 63, wid = tid >> 6;
  const int bid = blockIdx.x;
  const int gi = (bid & 7) | ((bid >> 7) << 3);  // 16 jt-wgs share gi
  const int jt = (bid >> 3) & 15;
  const int gl = (gi < 16) ? gi : gi - 16;
  const int m0 = (gi < 16) ? gi * 32 : 512 + gl * 32;
  const int l8 = lane & 7, ld8 = lane >> 3;
  const int swz = (l8 ^ ld8) * 8;

  // ---- one-time: W slice (4 gates x 32 rows x 512 K) -> w[2][16] per wave ----
  bf16x8 w[2][16];
#pragma unroll
  for (int kt = 0; kt < 8; ++kt) {
#pragma unroll
    for (int s = 0; s < 4; ++s) {
      int lr32 = s * 8 + ld8;
      int Wrow = wid * 512 + jt * 32 + lr32;
      async16(Whh + (size_t)Wrow * 512 + kt * 64 + swz,
              smem + wid * 4096 + s * 1024);
    }
    asm volatile("s_waitcnt vmcnt(0)" ::: "memory");
    __builtin_amdgcn_s_barrier();
    __builtin_amdgcn_sched_barrier(0);
    {
      const __hip_bfloat16* wb = (const __hip_bfloat16*)(smem + wid * 4096);
#pragma unroll
      for (int j = 0; j < 2; ++j) {
        int r = j * 16 + (lane & 15);
#pragma unroll
        for (int kkh = 0; kkh < 2; ++kkh)
          w[j][kt * 2 + kkh] =
              *(const bf16x8*)&wb[r * 64 + ((kkh * 32 + (lane >> 4) * 8) ^ ((r & 7) * 8))];
      }
    }
    __syncthreads();
  }

  // ---- one-time: XCD co-location vote (guarded fast path) ----
  int* flag = (int*)(smem + 49152);
  if (tid == 0) {
    int xcd = (int)(__builtin_amdgcn_s_getreg((31 << 11) | 20) & 15);  // HW_REG_XCC_ID
    int o1 = atomicOr(&ctr[512 + gi], 1 << xcd);
    int o2 = atomicOr(&ctr[561], 1 << xcd);
    asm volatile("" ::"v"(o1), "v"(o2));
    atomicAdd(&ctr[560], 1);
    while (__hip_atomic_load(&ctr[560], __ATOMIC_RELAXED, __HIP_MEMORY_SCOPE_AGENT) < 512)
      __builtin_amdgcn_s_sleep(2);
    int gm = __hip_atomic_load(&ctr[512 + gi], __ATOMIC_RELAXED, __HIP_MEMORY_SCOPE_AGENT);
    int am = __hip_atomic_load(&ctr[561], __ATOMIC_RELAXED, __HIP_MEMORY_SCOPE_AGENT);
    *flag = (__popc((unsigned)gm) == 1 && __popc((unsigned)am) == 8) ? 1 : 0;
  }
  __syncthreads();
  const bool fastpath = (*flag != 0);
  __syncthreads();

  // ownership / fragment constants
  const int rq = tid >> 5;        // row-quad 0..7
  const int col = tid & 31;       // h-col within jt slice
  const int i_x = (gl & 1) * 2 + (rq >> 2);
  const int wid_x = ((gl & 3) >> 1) * 2 + ((jt & 3) >> 1);
  const int j_x = (jt & 1) * 2 + (col >> 4);
  const int lane_x = ((rq & 3) << 4) | (col & 15);

  float bias_[4];
#pragma unroll
  for (int g = 0; g < 4; ++g) bias_[g] = biasL[g * 512 + jt * 32 + col];

  float c_[4];
#pragma unroll
  for (int e = 0; e < 4; ++e) c_[e] = 0.f;

  auto run = [&](auto FC) {
    constexpr bool FAST = decltype(FC)::v;
    constexpr int AUX = FAST ? 1 : 17;
    for (int t = 0; t < 64; ++t) {
      const __hip_bfloat16* hin = (t & 1) ? hB : hA;
      __hip_bfloat16* hout = (t & 1) ? hA : hB;

      // xp fragment loads FIRST (h-independent; latency hides under poll)
      const int TT = (gi < 16) ? t : 63 - t;
      const int bx = TT * 4 + (gl >> 2);
      u32x2 xg[4];
#pragma unroll
      for (int g = 0; g < 4; ++g) {
        int by = g * 4 + (jt >> 2);
        size_t slotP = (((size_t)bx * 16 + by) * 4 + wid_x) * 8 + i_x * 2 + (j_x >> 1);
        xg[g] = load8_pin((const char*)xp + slotP * 1024 + lane_x * 16 + (j_x & 1) * 8);
      }
      __builtin_amdgcn_sched_barrier(0);

      if (t > 0) {  // rendezvous: ONE batched agent-scope poll (proven optimum)
        if (wid == 0) {
          bool ok;
          do {
            int v = __hip_atomic_load(&ctr[gi * 16 + (lane & 15)], __ATOMIC_RELAXED,
                                      __HIP_MEMORY_SCOPE_AGENT);
            ok = __all(v >= t);
            if (!ok) __builtin_amdgcn_s_sleep(1);
          } while (!ok);
        }
        __syncthreads();
      }

      // stage the ENTIRE 32x512 A tile: 8 issues/thread, all in flight
#pragma unroll
      for (int kt = 0; kt < 8; ++kt)
        async16t<AUX>(hin + (size_t)(m0 + wid * 8 + ld8) * 512 + kt * 64 + swz,
                      smem + kt * 4096 + wid * 1024);
      __builtin_amdgcn_sched_barrier(0);

      f32x4 acc[2][2];
#pragma unroll
      for (int i = 0; i < 2; ++i)
#pragma unroll
        for (int j = 0; j < 2; ++j) acc[i][j] = {0.f, 0.f, 0.f, 0.f};

      auto do_kt = [&](int kt) {
        const __hip_bfloat16* ab = (const __hip_bfloat16*)(smem + kt * 4096);
#pragma unroll
        for (int kk = 0; kk < 64; kk += 32) {
          bf16x8 af[2];
#pragma unroll
          for (int i = 0; i < 2; ++i) {
            int r = i * 16 + (lane & 15);
            af[i] = *(const bf16x8*)&ab[r * 64 + ((kk + (lane >> 4) * 8) ^ ((r & 7) * 8))];
          }
#pragma unroll
          for (int i = 0; i < 2; ++i)
#pragma unroll
            for (int j = 0; j < 2; ++j)
              acc[i][j] = __builtin_amdgcn_mfma_f32_16x16x32_bf16(
                  af[i], w[j][kt * 2 + kk / 32], acc[i][j], 0, 0, 0);
        }
      };
      vmwait_barrier<4>();  // xp(4 oldest) + A0-3 retired; A4-7 in flight
#pragma unroll
      for (int kt = 0; kt < 4; ++kt) do_kt(kt);
      vmwait_barrier<0>();  // A4-7 retired
#pragma unroll
      for (int kt = 4; kt < 8; ++kt) do_kt(kt);

      // gate exchange: 16 planes x 1KB, b128 both sides (conflict-free)
      float* gsm = (float*)(smem + 32768);
      __syncthreads();
#pragma unroll
      for (int i = 0; i < 2; ++i)
#pragma unroll
        for (int j = 0; j < 2; ++j)
          *(f32x4*)(gsm + (wid * 4 + i * 2 + j) * 256 + lane * 4) = acc[i][j];
      __syncthreads();
      f32x4 gq[4];
      {
        const int iq = rq >> 2, jq = col >> 4;
        const int lprime = ((rq & 3) << 4) | (col & 15);
#pragma unroll
        for (int g = 0; g < 4; ++g)
          gq[g] = *(const f32x4*)(gsm + (g * 4 + iq * 2 + jq) * 256 + lprime * 4);
      }

      union { u32x2 v; __hip_bfloat16 h[4]; } X[4];
#pragma unroll
      for (int g = 0; g < 4; ++g) X[g].v = xg[g];
      __hip_bfloat16* hbase = hout + (size_t)(m0 + rq * 4) * 512 + jt * 32 + col;
#pragma unroll
      for (int rr = 0; rr < 4; ++rr) {
        float gi_ = gq[0][rr] + b2f(X[0].h[rr]) + bias_[0];
        float gf = gq[1][rr] + b2f(X[1].h[rr]) + bias_[1];
        float gg = gq[2][rr] + b2f(X[2].h[rr]) + bias_[2];
        float go = gq[3][rr] + b2f(X[3].h[rr]) + bias_[3];
        float cn = sigmf_(gf) * c_[rr] + sigmf_(gi_) * tanhf_(gg);
        float hn = sigmf_(go) * tanhf_(cn);
        c_[rr] = cn;
        union { __hip_bfloat16 b; unsigned short u; } hb;
        hb.b = f2b(hn);
        if constexpr (FAST) {
          hbase[rr * 512] = hb.b;  // plain store -> local L2 (same-XCD coherent)
        } else {
          storeh_coh(hbase + rr * 512, (unsigned int)hb.u);
        }
      }
      asm volatile("s_waitcnt vmcnt(0)" ::: "memory");  // h stores acked
      __syncthreads();                                   // whole wg's stores acked
      if (tid == 0)
        __hip_atomic_store(&ctr[gi * 16 + jt], t + 1, __ATOMIC_RELAXED,
                           __HIP_MEMORY_SCOPE_AGENT);
    }
  };
  if (fastpath) run(IC<1>{});
  else          run(IC<0>{});
}

// ---------------------------------------------------------------------------
__global__ void feat_kernel(const __hip_bfloat16* __restrict__ hA, float* __restrict__ feat) {
  int b = blockIdx.x;
  for (int c = threadIdx.x; c < 2048; c += 256) {
    int sec = c >> 9, j = c & 511;
    int row = (sec == 0) ? b : (sec == 1) ? 512 + b : (sec == 2) ? 256 + b : 768 + b;
    feat[b * 2048 + c] = b2f(hA[(size_t)row * 512 + j]);
  }
}

__global__ void bn_stats(const float* __restrict__ x, const float* __restrict__ g,
                         const float* __restrict__ b,
                         float* __restrict__ sc, float* __restrict__ sh) {
  int c = blockIdx.x * 256 + threadIdx.x;
  float s = 0.f, s2 = 0.f;
  for (int r = 0; r < 256; ++r) {
    float v = x[r * 2048 + c];
    s += v;
    s2 += v * v;
  }
  float mu = s * (1.f / 256.f);
  float var = s2 * (1.f / 256.f) - mu * mu;
  float rs = rsqrtf(var + 1e-5f);
  float scale = g[c] * rs;
  sc[c] = scale;
  sh[c] = b[c] - mu * scale;
}

__global__ void bn_apply(const float* __restrict__ x, const float* __restrict__ sc,
                         const float* __restrict__ sh, __hip_bfloat16* __restrict__ xn) {
  int i = blockIdx.x * 256 + threadIdx.x;
  int c = i & 2047;
  xn[i] = f2b(x[i] * sc[c] + sh[c]);
}

__global__ void final_kernel(const float* __restrict__ x2, const float* __restrict__ sc,
                             const float* __restrict__ sh, const float* __restrict__ Wo,
                             const float* __restrict__ bo, float* __restrict__ out) {
  __shared__ float red[3][256];
  int b = blockIdx.x, tid = threadIdx.x;
  float a0 = 0.f, a1 = 0.f, a2 = 0.f;
  for (int c = tid; c < 2048; c += 256) {
    float v = x2[b * 2048 + c] * sc[c] + sh[c];
    a0 += v * Wo[c];
    a1 += v * Wo[2048 + c];
    a2 += v * Wo[4096 + c];
  }
  red[0][tid] = a0; red[1][tid] = a1; red[2][tid] = a2;
  __syncthreads();
  for (int s = 128; s > 0; s >>= 1) {
    if (tid < s) {
      red[0][tid] += red[0][tid + s];
      red[1][tid] += red[1][tid + s];
      red[2][tid] += red[2][tid + s];
    }
    __syncthreads();
  }
  if (tid < 3) out[b * 3 + tid] = red[tid][0] + bo[tid];
}

// ---------------------------------------------------------------------------
extern "C" void kernel_launch(void* const* d_in, const int* in_sizes, int n_in,
                              void* d_out, int out_size, void* d_ws, size_t ws_size,
                              hipStream_t stream) {
  (void)in_sizes; (void)n_in; (void)out_size; (void)ws_size;
  const int* prem = (const int*)d_in[0];
  const int* hyp = (const int*)d_in[1];
  const float* embed = (const float*)d_in[2];
  const float* W_ih = (const float*)d_in[3];
  const float* W_hh = (const float*)d_in[4];
  const float* b_ih = (const float*)d_in[5];
  const float* b_hh = (const float*)d_in[6];
  const float* bn0g = (const float*)d_in[7];
  const float* bn0b = (const float*)d_in[8];
  const float* W0 = (const float*)d_in[9];
  const float* b0 = (const float*)d_in[10];
  const float* bn1g = (const float*)d_in[11];
  const float* bn1b = (const float*)d_in[12];
  const float* W1 = (const float*)d_in[13];
  const float* b1 = (const float*)d_in[14];
  const float* bnog = (const float*)d_in[15];
  const float* bnob = (const float*)d_in[16];
  const float* Wo = (const float*)d_in[17];
  const float* bo = (const float*)d_in[18];
  float* out = (float*)d_out;

  char* w = (char*)d_ws;
  size_t off = 0;
  auto alloc = [&](size_t bytes) {
    void* p = w + off;
    off += (bytes + 255) & ~(size_t)255;
    return p;
  };
  __hip_bfloat16* WihP = (__hip_bfloat16*)alloc((size_t)2048 * 320 * 2);
  __hip_bfloat16* Whhb = (__hip_bfloat16*)alloc((size_t)2048 * 512 * 2);
  __hip_bfloat16* W0b = (__hip_bfloat16*)alloc((size_t)2048 * 2048 * 2);
  __hip_bfloat16* W1b = (__hip_bfloat16*)alloc((size_t)2048 * 2048 * 2);
  float* biasL = (float*)alloc(2048 * 4);
  int* ctr = (int*)alloc(1024 * 4);
  __hip_bfloat16* xp = (__hip_bfloat16*)alloc((size_t)32768 * 2048 * 2);  // 128 MiB, fragment layout
  size_t ain_off = off;
  __hip_bfloat16* Ain = (__hip_bfloat16*)alloc((size_t)32768 * 320 * 2);  // 20 MiB
  size_t end_off = off;
  off = ain_off;  // post-GEMM block aliases Ain (dead after xproj)
  __hip_bfloat16* hA = (__hip_bfloat16*)alloc((size_t)1024 * 512 * 2);
  __hip_bfloat16* hB = (__hip_bfloat16*)alloc((size_t)1024 * 512 * 2);
  float* feat = (float*)alloc((size_t)256 * 2048 * 4);
  __hip_bfloat16* xn = (__hip_bfloat16*)alloc((size_t)256 * 2048 * 2);
  float* x1 = (float*)alloc((size_t)256 * 2048 * 4);
  float* x2 = (float*)alloc((size_t)256 * 2048 * 4);
  float* sc0 = (float*)alloc(2048 * 4);
  float* sh0 = (float*)alloc(2048 * 4);
  float* sc1 = (float*)alloc(2048 * 4);
  float* sh1 = (float*)alloc(2048 * 4);
  float* sc2 = (float*)alloc(2048 * 4);
  float* sh2 = (float*)alloc(2048 * 4);
  (void)end_off;

  (void)hipMemsetAsync(ctr, 0, 1024 * 4, stream);  // fresh barrier/vote state EVERY launch
  pack_weights<<<512, 256, 0, stream>>>(W_ih, W_hh, b_ih, b_hh, WihP, Whhb, biasL);
  cvt_f32_bf16<<<2048, 256, 0, stream>>>(W0, W0b, 2048 * 2048 / 4);
  cvt_f32_bf16<<<2048, 256, 0, stream>>>(W1, W1b, 2048 * 2048 / 4);
  gather_kernel<<<8192, 256, 0, stream>>>(prem, hyp, embed, Ain);
  // x_proj (N-major grid; paired-16B fragment layout): M=32768, N=2048, K=320
  gemm_pipe<128, 2><<<dim3(16, 256), 256, 0, stream>>>(Ain, WihP, biasL, xp, 320, 2048);
  (void)hipMemsetAsync(hA, 0, (size_t)1024 * 512 * 2, stream);  // h0 = 0 (aliases Ain)
  // persistent recurrence: 512 wgs, 48.2KB dyn LDS, 2 wg/CU
  (void)hipFuncSetAttribute(reinterpret_cast<const void*>(lstm_persist),
                            hipFuncAttributeMaxDynamicSharedMemorySize, 65536);
  lstm_persist<<<512, 256, 49408, stream>>>(xp, Whhb, biasL, hA, hB, ctr);
  feat_kernel<<<256, 256, 0, stream>>>(hA, feat);  // t=63 wrote hA
  bn_stats<<<8, 256, 0, stream>>>(feat, bn0g, bn0b, sc0, sh0);
  bn_apply<<<2048, 256, 0, stream>>>(feat, sc0, sh0, xn);
  gemm_pipe<64, 1><<<dim3(16, 4), 256, 0, stream>>>(xn, W0b, b0, x1, 2048, 2048);
  bn_stats<<<8, 256, 0, stream>>>(x1, bn1g, bn1b, sc1, sh1);
  bn_apply<<<2048, 256, 0, stream>>>(x1, sc1, sh1, xn);
  gemm_pipe<64, 1><<<dim3(16, 4), 256, 0, stream>>>(xn, W1b, b1, x2, 2048, 2048);
  bn_stats<<<8, 256, 0, stream>>>(x2, bnog, bnob, sc2, sh2);
  final_kernel<<<256, 256, 0, stream>>>(x2, sc2, sh2, Wo, bo, out);
}

// Round 17
// 421.875 us; speedup vs baseline: 3.0883x; 1.0495x over previous
//
#include <hip/hip_runtime.h>
#include <hip/hip_bf16.h>

// ConcatModel (all I/O f32; internal MFMA bf16, f32 accumulate):
// embed-gather(cvt) -> input-proj GEMM (N-major grid; paired-16B fragment xp)
// -> persistent LSTM recurrence (32 grps x 32 rows, 16 wgs/grp, 2 wg/CU;
// single batched agent-scope rendezvous, XCD-vote L2 fast path) ->
// fused BN(+feat-gather) -> GEMM+ReLU -> fused BN -> GEMM+ReLU -> BN -> out.
// R17: launch consolidation only (17 -> 12 dispatches); lstm/gemm unchanged.

typedef __attribute__((ext_vector_type(8))) short bf16x8;
typedef __attribute__((ext_vector_type(4))) float f32x4;
typedef __attribute__((ext_vector_type(2))) unsigned int u32x2;

#define DEVI __device__ __forceinline__

template<int N> struct IC { static constexpr int v = N; };

template<int AUX> DEVI void async16t(const void* g, void* l) {
  __builtin_amdgcn_global_load_lds((const __attribute__((address_space(1))) void*)g,
                                   (__attribute__((address_space(3))) void*)l,
                                   16, 0, AUX);
}
DEVI void async16(const void* g, void* l) { async16t<0>(g, l); }
DEVI u32x2 load8_pin(const void* addr) {
  u32x2 r;
  asm volatile("global_load_dwordx2 %0, %1, off" : "=v"(r) : "v"(addr) : "memory");
  return r;
}
DEVI void storeh_coh(void* a, unsigned int v) {
  asm volatile("global_store_short %0, %1, off sc0 sc1" ::"v"(a), "v"(v) : "memory");
}
template<int N> DEVI void vmwait_barrier() {
  asm volatile("s_waitcnt vmcnt(%0)" ::"i"(N) : "memory");
  __builtin_amdgcn_s_barrier();
  __builtin_amdgcn_sched_barrier(0);
}
DEVI float rcp_(float x) {
  float r;
  asm("v_rcp_f32 %0, %1" : "=v"(r) : "v"(x));
  return r;
}
DEVI float sigmf_(float x) { return rcp_(1.f + __expf(-x)); }
DEVI float tanhf_(float x) {
  float a = __expf(-2.f * fabsf(x));
  return copysignf((1.f - a) * rcp_(1.f + a), x);
}
DEVI __hip_bfloat16 f2b(float x) { return __float2bfloat16(x); }
DEVI float b2f(__hip_bfloat16 x) { return __bfloat162float(x); }

// ---------------------------------------------------------------------------
// pack W_ih (pad 300->320) + convert W_hh, W0, W1 + build biasL — ONE kernel
__global__ void pack_weights(const float* __restrict__ W_ih,
                             const float* __restrict__ W_hh,
                             const float* __restrict__ W0,
                             const float* __restrict__ W1,
                             const float* __restrict__ b_ih,
                             const float* __restrict__ b_hh,
                             __hip_bfloat16* __restrict__ WihP,
                             __hip_bfloat16* __restrict__ Whhb,
                             __hip_bfloat16* __restrict__ W0b,
                             __hip_bfloat16* __restrict__ W1b,
                             float* __restrict__ biasL) {
  int tid = blockIdx.x * 256 + threadIdx.x;
  int stride = gridDim.x * 256;
  for (int i = tid; i < 2048 * 320; i += stride) {
    int r = i / 320, c = i - r * 320;
    WihP[i] = (c < 300) ? f2b(W_ih[r * 300 + c]) : f2b(0.f);
  }
  for (int i = tid; i < 2048 * 512 / 4; i += stride) {
    float4 v = ((const float4*)W_hh)[i];
    union { __hip_bfloat16 h[4]; uint2 u; } o;
    o.h[0] = f2b(v.x); o.h[1] = f2b(v.y); o.h[2] = f2b(v.z); o.h[3] = f2b(v.w);
    ((uint2*)Whhb)[i] = o.u;
  }
  for (int i = tid; i < 2048 * 2048 / 4; i += stride) {
    float4 v = ((const float4*)W0)[i];
    union { __hip_bfloat16 h[4]; uint2 u; } o;
    o.h[0] = f2b(v.x); o.h[1] = f2b(v.y); o.h[2] = f2b(v.z); o.h[3] = f2b(v.w);
    ((uint2*)W0b)[i] = o.u;
    float4 w1 = ((const float4*)W1)[i];
    o.h[0] = f2b(w1.x); o.h[1] = f2b(w1.y); o.h[2] = f2b(w1.z); o.h[3] = f2b(w1.w);
    ((uint2*)W1b)[i] = o.u;
  }
  if (tid < 2048) biasL[tid] = b_ih[tid] + b_hh[tid];
}

__global__ void gather_kernel(const int* __restrict__ prem, const int* __restrict__ hyp,
                              const float* __restrict__ embed,
                              __hip_bfloat16* __restrict__ Ain) {
  int row = blockIdx.x * 4 + (threadIdx.x >> 6);
  int lane = threadIdx.x & 63;
  int tt = row >> 9, n = row & 511;
  int tok = (n < 256) ? prem[tt * 256 + n] : hyp[tt * 256 + (n - 256)];
  const float4* e4 = (const float4*)(embed + (size_t)tok * 300);  // 75 x 16B
  uint2* d2 = (uint2*)(Ain + (size_t)row * 320);                  // 80 x 8B
  for (int j = lane; j < 75; j += 64) {
    float4 v = e4[j];
    union { __hip_bfloat16 h[4]; uint2 u; } o;
    o.h[0] = f2b(v.x); o.h[1] = f2b(v.y); o.h[2] = f2b(v.z); o.h[3] = f2b(v.w);
    d2[j] = o.u;
  }
  for (int j = 75 + lane; j < 80; j += 64) d2[j] = make_uint2(0u, 0u);
}

// ---------------------------------------------------------------------------
// Pipelined GEMM, N-MAJOR GRID (unchanged from R16). EPI=1: f32+bias+relu.
// EPI=2: bf16 fragment layout, paired 16B stores.
template<int BM, int EPI>
__global__ __launch_bounds__(256)
void gemm_pipe(const __hip_bfloat16* __restrict__ A,
               const __hip_bfloat16* __restrict__ Bn,
               const float* __restrict__ bias,
               void* __restrict__ Cout, int K, int ldc) {
  constexpr int BK = 64;
  constexpr int ABYT = BM * BK * 2;
  constexpr int BBYT = 128 * BK * 2;
  constexpr int APW = BM / 32;
  constexpr int IFL = APW + 4;
  constexpr int WM = BM / 2, MT = WM / 16;
  __shared__ alignas(16) char smem[2 * ABYT + 2 * BBYT];

  const int tid = threadIdx.x, lane = tid & 63, wid = tid >> 6;
  const int wrow = wid >> 1, wcol = wid & 1;
  const int bx = blockIdx.y, by = blockIdx.x;  // N-major
  const int m0 = bx * BM, n0 = by * 128;
  const int l8 = lane & 7, ld8 = lane >> 3;
  const int swz = (l8 ^ ld8) * 8;

  const __hip_bfloat16* Abase = A + (size_t)m0 * K;
  const __hip_bfloat16* Bbase = Bn + (size_t)n0 * K;

  f32x4 acc[MT][4];
#pragma unroll
  for (int i = 0; i < MT; ++i)
#pragma unroll
    for (int j = 0; j < 4; ++j) acc[i][j] = {0.f, 0.f, 0.f, 0.f};

  auto stage = [&](int buf, int kt) {
    const __hip_bfloat16* as = Abase + kt * BK + swz;
    char* ad = smem + buf * ABYT;
#pragma unroll
    for (int s = 0; s < APW; ++s) {
      int iss = wid * APW + s;
      async16(as + (size_t)(iss * 8 + ld8) * K, ad + iss * 1024);
    }
    const __hip_bfloat16* bs = Bbase + kt * BK + swz;
    char* bd = smem + 2 * ABYT + buf * BBYT;
#pragma unroll
    for (int s = 0; s < 4; ++s) {
      int iss = wid * 4 + s;
      async16(bs + (size_t)(iss * 8 + ld8) * K, bd + iss * 1024);
    }
  };

  const int nk = K / BK;
  stage(0, 0);
  for (int kt = 0; kt < nk; ++kt) {
    if (kt + 1 < nk) {
      stage((kt + 1) & 1, kt + 1);
      vmwait_barrier<IFL>();
    } else {
      vmwait_barrier<0>();
    }
    const __hip_bfloat16* ab = (const __hip_bfloat16*)(smem + (kt & 1) * ABYT);
    const __hip_bfloat16* bb = (const __hip_bfloat16*)(smem + 2 * ABYT + (kt & 1) * BBYT);
#pragma unroll
    for (int kk = 0; kk < BK; kk += 32) {
      bf16x8 af[MT], bf[4];
#pragma unroll
      for (int i = 0; i < MT; ++i) {
        int r = wrow * WM + i * 16 + (lane & 15);
        af[i] = *(const bf16x8*)&ab[r * BK + ((kk + (lane >> 4) * 8) ^ ((r & 7) * 8))];
      }
#pragma unroll
      for (int j = 0; j < 4; ++j) {
        int r = wcol * 64 + j * 16 + (lane & 15);
        bf[j] = *(const bf16x8*)&bb[r * BK + ((kk + (lane >> 4) * 8) ^ ((r & 7) * 8))];
      }
#pragma unroll
      for (int i = 0; i < MT; ++i)
#pragma unroll
        for (int j = 0; j < 4; ++j)
          acc[i][j] = __builtin_amdgcn_mfma_f32_16x16x32_bf16(af[i], bf[j], acc[i][j], 0, 0, 0);
    }
    __builtin_amdgcn_s_barrier();
  }

  if (EPI == 2) {
#pragma unroll
    for (int i = 0; i < MT; ++i)
#pragma unroll
      for (int jp = 0; jp < 2; ++jp) {
        union { __hip_bfloat16 h[8]; uint4 u; } o;
#pragma unroll
        for (int rr = 0; rr < 4; ++rr) {
          o.h[rr] = f2b(acc[i][2 * jp][rr]);
          o.h[4 + rr] = f2b(acc[i][2 * jp + 1][rr]);
        }
        size_t slotP = (((size_t)bx * 16 + by) * 4 + wid) * 8 + i * 2 + jp;
        *(uint4*)((char*)Cout + slotP * 1024 + lane * 16) = o.u;
      }
    return;
  }

  __syncthreads();
  float* Csm = (float*)smem;
#pragma unroll
  for (int i = 0; i < MT; ++i)
#pragma unroll
    for (int j = 0; j < 4; ++j)
#pragma unroll
      for (int rr = 0; rr < 4; ++rr) {
        int row = wrow * WM + i * 16 + (lane >> 4) * 4 + rr;
        int col = wcol * 64 + j * 16 + (lane & 15);
        Csm[row * 128 + (col ^ ((row & 7) << 2))] = acc[i][j][rr];
      }
  __syncthreads();
#pragma unroll
  for (int it = 0; it < BM / 16; ++it) {
    int idx = it * 256 + tid;
    int row = idx >> 4;
    int cb = (idx & 15) * 8;
    int sw = (row & 7) << 2;
    float4 v0 = *(const float4*)&Csm[row * 128 + (cb ^ sw)];
    float4 v1 = *(const float4*)&Csm[row * 128 + ((cb + 4) ^ sw)];
    float4 b0 = *(const float4*)&bias[n0 + cb];
    float4 b1 = *(const float4*)&bias[n0 + cb + 4];
    v0.x = fmaxf(v0.x + b0.x, 0.f); v0.y = fmaxf(v0.y + b0.y, 0.f);
    v0.z = fmaxf(v0.z + b0.z, 0.f); v0.w = fmaxf(v0.w + b0.w, 0.f);
    v1.x = fmaxf(v1.x + b1.x, 0.f); v1.y = fmaxf(v1.y + b1.y, 0.f);
    v1.z = fmaxf(v1.z + b1.z, 0.f); v1.w = fmaxf(v1.w + b1.w, 0.f);
    size_t base = (size_t)(m0 + row) * ldc + n0 + cb;
    *(float4*)&((float*)Cout)[base] = v0;
    *(float4*)&((float*)Cout)[base + 4] = v1;
  }
}

// ---------------------------------------------------------------------------
// Persistent recurrence (byte-identical to verified R16 structure).
__global__ __launch_bounds__(256, 2)
void lstm_persist(const __hip_bfloat16* __restrict__ xp,
                  const __hip_bfloat16* __restrict__ Whh,
                  const float* __restrict__ biasL,
                  __hip_bfloat16* __restrict__ hA,
                  __hip_bfloat16* __restrict__ hB,
                  int* __restrict__ ctr) {
  extern __shared__ char smem[];
  const int tid = threadIdx.x, lane = tid & 63, wid = tid >> 6;
  const int bid = blockIdx.x;
  const int gi = (bid & 7) | ((bid >> 7) << 3);  // 16 jt-wgs share gi
  const int jt = (bid >> 3) & 15;
  const int gl = (gi < 16) ? gi : gi - 16;
  const int m0 = (gi < 16) ? gi * 32 : 512 + gl * 32;
  const int l8 = lane & 7, ld8 = lane >> 3;
  const int swz = (l8 ^ ld8) * 8;

  // ---- one-time: W slice (4 gates x 32 rows x 512 K) -> w[2][16] per wave ----
  bf16x8 w[2][16];
#pragma unroll
  for (int kt = 0; kt < 8; ++kt) {
#pragma unroll
    for (int s = 0; s < 4; ++s) {
      int lr32 = s * 8 + ld8;
      int Wrow = wid * 512 + jt * 32 + lr32;
      async16(Whh + (size_t)Wrow * 512 + kt * 64 + swz,
              smem + wid * 4096 + s * 1024);
    }
    asm volatile("s_waitcnt vmcnt(0)" ::: "memory");
    __builtin_amdgcn_s_barrier();
    __builtin_amdgcn_sched_barrier(0);
    {
      const __hip_bfloat16* wb = (const __hip_bfloat16*)(smem + wid * 4096);
#pragma unroll
      for (int j = 0; j < 2; ++j) {
        int r = j * 16 + (lane & 15);
#pragma unroll
        for (int kkh = 0; kkh < 2; ++kkh)
          w[j][kt * 2 + kkh] =
              *(const bf16x8*)&wb[r * 64 + ((kkh * 32 + (lane >> 4) * 8) ^ ((r & 7) * 8))];
      }
    }
    __syncthreads();
  }

  // ---- one-time: XCD co-location vote (guarded fast path) ----
  int* flag = (int*)(smem + 49152);
  if (tid == 0) {
    int xcd = (int)(__builtin_amdgcn_s_getreg((31 << 11) | 20) & 15);  // HW_REG_XCC_ID
    int o1 = atomicOr(&ctr[512 + gi], 1 << xcd);
    int o2 = atomicOr(&ctr[561], 1 << xcd);
    asm volatile("" ::"v"(o1), "v"(o2));
    atomicAdd(&ctr[560], 1);
    while (__hip_atomic_load(&ctr[560], __ATOMIC_RELAXED, __HIP_MEMORY_SCOPE_AGENT) < 512)
      __builtin_amdgcn_s_sleep(2);
    int gm = __hip_atomic_load(&ctr[512 + gi], __ATOMIC_RELAXED, __HIP_MEMORY_SCOPE_AGENT);
    int am = __hip_atomic_load(&ctr[561], __ATOMIC_RELAXED, __HIP_MEMORY_SCOPE_AGENT);
    *flag = (__popc((unsigned)gm) == 1 && __popc((unsigned)am) == 8) ? 1 : 0;
  }
  __syncthreads();
  const bool fastpath = (*flag != 0);
  __syncthreads();

  // ownership / fragment constants
  const int rq = tid >> 5;        // row-quad 0..7
  const int col = tid & 31;       // h-col within jt slice
  const int i_x = (gl & 1) * 2 + (rq >> 2);
  const int wid_x = ((gl & 3) >> 1) * 2 + ((jt & 3) >> 1);
  const int j_x = (jt & 1) * 2 + (col >> 4);
  const int lane_x = ((rq & 3) << 4) | (col & 15);

  float bias_[4];
#pragma unroll
  for (int g = 0; g < 4; ++g) bias_[g] = biasL[g * 512 + jt * 32 + col];

  float c_[4];
#pragma unroll
  for (int e = 0; e < 4; ++e) c_[e] = 0.f;

  auto run = [&](auto FC) {
    constexpr bool FAST = decltype(FC)::v;
    constexpr int AUX = FAST ? 1 : 17;
    for (int t = 0; t < 64; ++t) {
      const __hip_bfloat16* hin = (t & 1) ? hB : hA;
      __hip_bfloat16* hout = (t & 1) ? hA : hB;

      // xp fragment loads FIRST (h-independent; latency hides under poll)
      const int TT = (gi < 16) ? t : 63 - t;
      const int bx = TT * 4 + (gl >> 2);
      u32x2 xg[4];
#pragma unroll
      for (int g = 0; g < 4; ++g) {
        int by = g * 4 + (jt >> 2);
        size_t slotP = (((size_t)bx * 16 + by) * 4 + wid_x) * 8 + i_x * 2 + (j_x >> 1);
        xg[g] = load8_pin((const char*)xp + slotP * 1024 + lane_x * 16 + (j_x & 1) * 8);
      }
      __builtin_amdgcn_sched_barrier(0);

      if (t > 0) {  // rendezvous: ONE batched agent-scope poll (proven optimum)
        if (wid == 0) {
          bool ok;
          do {
            int v = __hip_atomic_load(&ctr[gi * 16 + (lane & 15)], __ATOMIC_RELAXED,
                                      __HIP_MEMORY_SCOPE_AGENT);
            ok = __all(v >= t);
            if (!ok) __builtin_amdgcn_s_sleep(1);
          } while (!ok);
        }
        __syncthreads();
      }

      // stage the ENTIRE 32x512 A tile: 8 issues/thread, all in flight
#pragma unroll
      for (int kt = 0; kt < 8; ++kt)
        async16t<AUX>(hin + (size_t)(m0 + wid * 8 + ld8) * 512 + kt * 64 + swz,
                      smem + kt * 4096 + wid * 1024);
      __builtin_amdgcn_sched_barrier(0);

      f32x4 acc[2][2];
#pragma unroll
      for (int i = 0; i < 2; ++i)
#pragma unroll
        for (int j = 0; j < 2; ++j) acc[i][j] = {0.f, 0.f, 0.f, 0.f};

      auto do_kt = [&](int kt) {
        const __hip_bfloat16* ab = (const __hip_bfloat16*)(smem + kt * 4096);
#pragma unroll
        for (int kk = 0; kk < 64; kk += 32) {
          bf16x8 af[2];
#pragma unroll
          for (int i = 0; i < 2; ++i) {
            int r = i * 16 + (lane & 15);
            af[i] = *(const bf16x8*)&ab[r * 64 + ((kk + (lane >> 4) * 8) ^ ((r & 7) * 8))];
          }
#pragma unroll
          for (int i = 0; i < 2; ++i)
#pragma unroll
            for (int j = 0; j < 2; ++j)
              acc[i][j] = __builtin_amdgcn_mfma_f32_16x16x32_bf16(
                  af[i], w[j][kt * 2 + kk / 32], acc[i][j], 0, 0, 0);
        }
      };
      vmwait_barrier<4>();  // xp(4 oldest) + A0-3 retired; A4-7 in flight
#pragma unroll
      for (int kt = 0; kt < 4; ++kt) do_kt(kt);
      vmwait_barrier<0>();  // A4-7 retired
#pragma unroll
      for (int kt = 4; kt < 8; ++kt) do_kt(kt);

      // gate exchange: 16 planes x 1KB, b128 both sides (conflict-free)
      float* gsm = (float*)(smem + 32768);
      __syncthreads();
#pragma unroll
      for (int i = 0; i < 2; ++i)
#pragma unroll
        for (int j = 0; j < 2; ++j)
          *(f32x4*)(gsm + (wid * 4 + i * 2 + j) * 256 + lane * 4) = acc[i][j];
      __syncthreads();
      f32x4 gq[4];
      {
        const int iq = rq >> 2, jq = col >> 4;
        const int lprime = ((rq & 3) << 4) | (col & 15);
#pragma unroll
        for (int g = 0; g < 4; ++g)
          gq[g] = *(const f32x4*)(gsm + (g * 4 + iq * 2 + jq) * 256 + lprime * 4);
      }

      union { u32x2 v; __hip_bfloat16 h[4]; } X[4];
#pragma unroll
      for (int g = 0; g < 4; ++g) X[g].v = xg[g];
      __hip_bfloat16* hbase = hout + (size_t)(m0 + rq * 4) * 512 + jt * 32 + col;
#pragma unroll
      for (int rr = 0; rr < 4; ++rr) {
        float gi_ = gq[0][rr] + b2f(X[0].h[rr]) + bias_[0];
        float gf = gq[1][rr] + b2f(X[1].h[rr]) + bias_[1];
        float gg = gq[2][rr] + b2f(X[2].h[rr]) + bias_[2];
        float go = gq[3][rr] + b2f(X[3].h[rr]) + bias_[3];
        float cn = sigmf_(gf) * c_[rr] + sigmf_(gi_) * tanhf_(gg);
        float hn = sigmf_(go) * tanhf_(cn);
        c_[rr] = cn;
        union { __hip_bfloat16 b; unsigned short u; } hb;
        hb.b = f2b(hn);
        if constexpr (FAST) {
          hbase[rr * 512] = hb.b;  // plain store -> local L2 (same-XCD coherent)
        } else {
          storeh_coh(hbase + rr * 512, (unsigned int)hb.u);
        }
      }
      asm volatile("s_waitcnt vmcnt(0)" ::: "memory");  // h stores acked
      __syncthreads();                                   // whole wg's stores acked
      if (tid == 0)
        __hip_atomic_store(&ctr[gi * 16 + jt], t + 1, __ATOMIC_RELAXED,
                           __HIP_MEMORY_SCOPE_AGENT);
    }
  };
  if (fastpath) run(IC<1>{});
  else          run(IC<0>{});
}

// ---------------------------------------------------------------------------
// Fused BN (stats + apply), per-column independence: each wg owns 8 full
// columns. SRC=0: input = final h (bf16, feat index mapping, no feat buffer);
// SRC=1: input = f32 row-major [256][2048]. Output xn bf16 [256][2048].
template<int SRC>
__global__ void bn_fused(const void* __restrict__ xin,
                         const float* __restrict__ g,
                         const float* __restrict__ b,
                         __hip_bfloat16* __restrict__ xn) {
  __shared__ float sred[8][32], s2red[8][32];
  __shared__ float scs[8], shs[8];
  const int t = threadIdx.x;
  const int cidx = t & 7;         // column within wg
  const int rchunk = t >> 3;      // 0..31 -> rows rchunk*8..+7
  const int c = blockIdx.x * 8 + cidx;
  const int sec = c >> 9, jcol = c & 511;
  const int rowoff = (sec == 0) ? 0 : (sec == 1) ? 512 : (sec == 2) ? 256 : 768;

  float vals[8];
  float s = 0.f, s2 = 0.f;
#pragma unroll
  for (int rr = 0; rr < 8; ++rr) {
    int r = rchunk * 8 + rr;
    float v;
    if (SRC == 0) {
      v = b2f(((const __hip_bfloat16*)xin)[(size_t)(rowoff + r) * 512 + jcol]);
    } else {
      v = ((const float*)xin)[(size_t)r * 2048 + c];
    }
    vals[rr] = v;
    s += v;
    s2 += v * v;
  }
  sred[cidx][rchunk] = s;
  s2red[cidx][rchunk] = s2;
  __syncthreads();
  if (t < 8) {
    float ts = 0.f, ts2 = 0.f;
#pragma unroll
    for (int k = 0; k < 32; ++k) { ts += sred[t][k]; ts2 += s2red[t][k]; }
    float mu = ts * (1.f / 256.f);
    float var = ts2 * (1.f / 256.f) - mu * mu;
    float rs = rsqrtf(var + 1e-5f);
    float scale = g[blockIdx.x * 8 + t] * rs;
    scs[t] = scale;
    shs[t] = b[blockIdx.x * 8 + t] - mu * scale;
  }
  __syncthreads();
  const float scale = scs[cidx], shift = shs[cidx];
#pragma unroll
  for (int rr = 0; rr < 8; ++rr) {
    int r = rchunk * 8 + rr;
    xn[(size_t)r * 2048 + c] = f2b(vals[rr] * scale + shift);
  }
}

__global__ void bn_stats(const float* __restrict__ x, const float* __restrict__ g,
                         const float* __restrict__ b,
                         float* __restrict__ sc, float* __restrict__ sh) {
  int c = blockIdx.x * 256 + threadIdx.x;
  float s = 0.f, s2 = 0.f;
  for (int r = 0; r < 256; ++r) {
    float v = x[r * 2048 + c];
    s += v;
    s2 += v * v;
  }
  float mu = s * (1.f / 256.f);
  float var = s2 * (1.f / 256.f) - mu * mu;
  float rs = rsqrtf(var + 1e-5f);
  float scale = g[c] * rs;
  sc[c] = scale;
  sh[c] = b[c] - mu * scale;
}

__global__ void final_kernel(const float* __restrict__ x2, const float* __restrict__ sc,
                             const float* __restrict__ sh, const float* __restrict__ Wo,
                             const float* __restrict__ bo, float* __restrict__ out) {
  __shared__ float red[3][256];
  int b = blockIdx.x, tid = threadIdx.x;
  float a0 = 0.f, a1 = 0.f, a2 = 0.f;
  for (int c = tid; c < 2048; c += 256) {
    float v = x2[b * 2048 + c] * sc[c] + sh[c];
    a0 += v * Wo[c];
    a1 += v * Wo[2048 + c];
    a2 += v * Wo[4096 + c];
  }
  red[0][tid] = a0; red[1][tid] = a1; red[2][tid] = a2;
  __syncthreads();
  for (int s = 128; s > 0; s >>= 1) {
    if (tid < s) {
      red[0][tid] += red[0][tid + s];
      red[1][tid] += red[1][tid + s];
      red[2][tid] += red[2][tid + s];
    }
    __syncthreads();
  }
  if (tid < 3) out[b * 3 + tid] = red[tid][0] + bo[tid];
}

// ---------------------------------------------------------------------------
extern "C" void kernel_launch(void* const* d_in, const int* in_sizes, int n_in,
                              void* d_out, int out_size, void* d_ws, size_t ws_size,
                              hipStream_t stream) {
  (void)in_sizes; (void)n_in; (void)out_size; (void)ws_size;
  const int* prem = (const int*)d_in[0];
  const int* hyp = (const int*)d_in[1];
  const float* embed = (const float*)d_in[2];
  const float* W_ih = (const float*)d_in[3];
  const float* W_hh = (const float*)d_in[4];
  const float* b_ih = (const float*)d_in[5];
  const float* b_hh = (const float*)d_in[6];
  const float* bn0g = (const float*)d_in[7];
  const float* bn0b = (const float*)d_in[8];
  const float* W0 = (const float*)d_in[9];
  const float* b0 = (const float*)d_in[10];
  const float* bn1g = (const float*)d_in[11];
  const float* bn1b = (const float*)d_in[12];
  const float* W1 = (const float*)d_in[13];
  const float* b1 = (const float*)d_in[14];
  const float* bnog = (const float*)d_in[15];
  const float* bnob = (const float*)d_in[16];
  const float* Wo = (const float*)d_in[17];
  const float* bo = (const float*)d_in[18];
  float* out = (float*)d_out;

  char* w = (char*)d_ws;
  size_t off = 0;
  auto alloc = [&](size_t bytes) {
    void* p = w + off;
    off += (bytes + 255) & ~(size_t)255;
    return p;
  };
  __hip_bfloat16* WihP = (__hip_bfloat16*)alloc((size_t)2048 * 320 * 2);
  __hip_bfloat16* Whhb = (__hip_bfloat16*)alloc((size_t)2048 * 512 * 2);
  __hip_bfloat16* W0b = (__hip_bfloat16*)alloc((size_t)2048 * 2048 * 2);
  __hip_bfloat16* W1b = (__hip_bfloat16*)alloc((size_t)2048 * 2048 * 2);
  float* biasL = (float*)alloc(2048 * 4);
  int* ctr = (int*)alloc(1024 * 4);
  __hip_bfloat16* xp = (__hip_bfloat16*)alloc((size_t)32768 * 2048 * 2);  // 128 MiB, fragment layout
  size_t ain_off = off;
  __hip_bfloat16* Ain = (__hip_bfloat16*)alloc((size_t)32768 * 320 * 2);  // 20 MiB
  size_t end_off = off;
  off = ain_off;  // post-GEMM block aliases Ain (dead after xproj)
  __hip_bfloat16* hA = (__hip_bfloat16*)alloc((size_t)1024 * 512 * 2);
  __hip_bfloat16* hB = (__hip_bfloat16*)alloc((size_t)1024 * 512 * 2);
  __hip_bfloat16* xn = (__hip_bfloat16*)alloc((size_t)256 * 2048 * 2);
  float* x1 = (float*)alloc((size_t)256 * 2048 * 4);
  float* x2 = (float*)alloc((size_t)256 * 2048 * 4);
  float* sc2 = (float*)alloc(2048 * 4);
  float* sh2 = (float*)alloc(2048 * 4);
  (void)end_off;

  (void)hipMemsetAsync(ctr, 0, 1024 * 4, stream);  // fresh barrier/vote state EVERY launch
  pack_weights<<<512, 256, 0, stream>>>(W_ih, W_hh, W0, W1, b_ih, b_hh,
                                        WihP, Whhb, W0b, W1b, biasL);
  gather_kernel<<<8192, 256, 0, stream>>>(prem, hyp, embed, Ain);
  // x_proj (N-major grid; paired-16B fragment layout): M=32768, N=2048, K=320
  gemm_pipe<128, 2><<<dim3(16, 256), 256, 0, stream>>>(Ain, WihP, biasL, xp, 320, 2048);
  (void)hipMemsetAsync(hA, 0, (size_t)1024 * 512 * 2, stream);  // h0 = 0 (aliases Ain)
  // persistent recurrence: 512 wgs, 48.2KB dyn LDS, 2 wg/CU
  (void)hipFuncSetAttribute(reinterpret_cast<const void*>(lstm_persist),
                            hipFuncAttributeMaxDynamicSharedMemorySize, 65536);
  lstm_persist<<<512, 256, 49408, stream>>>(xp, Whhb, biasL, hA, hB, ctr);
  // head: fused BN (feat-gather from hA) -> GEMM+ReLU -> fused BN -> GEMM+ReLU
  bn_fused<0><<<256, 256, 0, stream>>>(hA, bn0g, bn0b, xn);
  gemm_pipe<64, 1><<<dim3(16, 4), 256, 0, stream>>>(xn, W0b, b0, x1, 2048, 2048);
  bn_fused<1><<<256, 256, 0, stream>>>(x1, bn1g, bn1b, xn);
  gemm_pipe<64, 1><<<dim3(16, 4), 256, 0, stream>>>(xn, W1b, b1, x2, 2048, 2048);
  bn_stats<<<8, 256, 0, stream>>>(x2, bnog, bnob, sc2, sh2);
  final_kernel<<<256, 256, 0, stream>>>(x2, sc2, sh2, Wo, bo, out);
}